// Round 8
// baseline (1038.327 us; speedup 1.0000x reference)
//
#include <hip/hip_runtime.h>

typedef unsigned short u16;
typedef unsigned int u32;
typedef unsigned long long u64;

#define B_TOTAL 65536
#define H 512
#define D 64
#define BM 64

typedef __bf16 bf16x8 __attribute__((ext_vector_type(8)));
typedef float f32x4 __attribute__((ext_vector_type(4)));

__device__ __forceinline__ u32 f2b(float f) {  // fp32 -> bf16 bits, RNE
  u32 u = __builtin_bit_cast(u32, f);
  return (u + 0x7fffu + ((u >> 16) & 1u)) >> 16;
}
__device__ __forceinline__ float b2f(u32 bits) {
  return __builtin_bit_cast(float, bits << 16);
}

// ---- workspace layout (bf16 element offsets) ----
// Weight regions are FRAGMENT-PACKED: for logical B-matrix M[NN][KK],
// packed[( (n>>4)*(KK/32) + (k>>5) )*512 + lane*8 + j] = M[n][k],
// n = ntile*16 + (lane&15), k = kstep*32 + (lane>>4)*8 + j.
#define OFF_Wz0b 0          /* [N=512][K=64]  fwd L0 */
#define OFF_Wx0b 32768
#define OFF_Wx1b 65536
#define OFF_Wx2b 98304
#define OFF_Wz1b 131072     /* [N=512][K=512] fwd */
#define OFF_Wz2b 393216
#define OFF_Wz3b 655360
#define OFF_Wz1t 917504     /* [N=512][K=512] transposed, bwd */
#define OFF_Wz2t 1179648
#define OFF_Wz3t 1441792
#define OFF_Wz0t 1703936    /* [N=64][K=512] transposed grad weights */
#define OFF_Wx0t 1736704
#define OFF_Wx1t 1769472
#define OFF_Wx2t 1802240
#define OFF_WEND 1835008
#define SLAB_ELEMS (B_TOTAL * H)          /* 33,554,432 bf16 per slab */
#define OFF_S0 OFF_WEND
#define OFF_S1 (OFF_S0 + SLAB_ELEMS)
#define OFF_S2 (OFF_S1 + SLAB_ELEMS)
#define WS_ELEMS (OFF_S2 + SLAB_ELEMS)    /* ~102.5M elems = ~205 MB */

// ---- weight prep: fp32 -> bf16, fragment-packed (+ transposed variants) ----
__global__ __launch_bounds__(256) void prep_kernel(
    const float* __restrict__ Wz0, const float* __restrict__ Wz1,
    const float* __restrict__ Wz2, const float* __restrict__ Wz3,
    const float* __restrict__ Wx0, const float* __restrict__ Wx1,
    const float* __restrict__ Wx2, u16* __restrict__ wsb) {
  int i = blockIdx.x * 256 + threadIdx.x;   // grid exactly covers OFF_WEND
  const float* src;
  int NN, KK, trans, p;
  if (i < 131072) {                          // x-path fwd: [512][64] direct
    int r = i >> 15; p = i & 32767;
    src = (r == 0) ? Wz0 : (r == 1) ? Wx0 : (r == 2) ? Wx1 : Wx2;
    NN = 512; KK = 64; trans = 0;
  } else if (i < 917504) {                   // H fwd: [512][512] direct
    int j = i - 131072; int r = j >> 18; p = j & 262143;
    src = (r == 0) ? Wz1 : (r == 1) ? Wz2 : Wz3;
    NN = 512; KK = 512; trans = 0;
  } else if (i < 1703936) {                  // H bwd: transposed
    int j = i - 917504; int r = j >> 18; p = j & 262143;
    src = (r == 0) ? Wz1 : (r == 1) ? Wz2 : Wz3;
    NN = 512; KK = 512; trans = 1;
  } else {                                   // grad weights: [64][512] = W^T
    int j = i - 1703936; int r = j >> 15; p = j & 32767;
    src = (r == 0) ? Wz0 : (r == 1) ? Wx0 : (r == 2) ? Wx1 : Wx2;
    NN = 64; KK = 512; trans = 1;
  }
  int jj = p & 7, lane = (p >> 3) & 63, blk = p >> 9;
  int kt_sh = (KK == 64) ? 1 : 4;            // log2(KK/32)
  int ntile = blk >> kt_sh;
  int kstep = blk & ((1 << kt_sh) - 1);
  int n = ntile * 16 + (lane & 15);
  int k = kstep * 32 + ((lane >> 4) << 3) + jj;
  float v = trans ? src[k * NN + n] : src[n * KK + k];
  wsb[i] = (u16)f2b(v);
}

__global__ __launch_bounds__(256) void fill_sentinel(float* out, int n) {
  int i = blockIdx.x * 256 + threadIdx.x;
  if (i < n) out[i] = 12345.0f;   // unmistakable "workspace too small" marker
}

// ---- fused ICNN fwd + bwd-through-Wz; grad side-terms split out ----
// block = 256 thr (4 waves), BM=64 rows; wave w owns cols [w*128,+128) of the
// [64,512] GEMMs (acc[4][8]).
// R8: depth-2 full-step weight prefetch (b0/b1, 64 VGPR): issue->consume
// distance ~1240 cyc (2-wave interleave) > ~900-cyc HBM-miss latency, so the
// K-loop no longer exposes weight-load latency even though per-phase weights
// are cold in the slab-write-thrashed L2. Legal now that acc=128 (no gacc).
__global__ __launch_bounds__(256, 2) void icnn_kernel(
    const float* __restrict__ state,
    const float* __restrict__ bz0, const float* __restrict__ bx0,
    const float* __restrict__ bx1, const float* __restrict__ bx2,
    const float* __restrict__ WzL, const float* __restrict__ WxL,
    u16* __restrict__ wsw, float* __restrict__ out) {
  __shared__ u16 zbuf[BM * H];    // XOR-swizzled activations, 64 KB
  // x staging needs BM*72 u16 = 9216 B; t3 park needs 1024 u64 = 8192 B.
  __shared__ u64 xb64[BM * 18];
  u16* xbuf = (u16*)xb64;

  const int tid = threadIdx.x;
  const int w = tid >> 6;
  const int lane = tid & 63;
  const int l15 = lane & 15;
  const int q = lane >> 4;
  const int blk = blockIdx.x;
  const int blk4w = blk * 4 + w;

  const u16* Wz0b = wsw + OFF_Wz0b;
  const u16* Wx0b = wsw + OFF_Wx0b;
  const u16* Wx1b = wsw + OFF_Wx1b;
  const u16* Wx2b = wsw + OFF_Wx2b;
  const u16* Wz1b = wsw + OFF_Wz1b;
  const u16* Wz2b = wsw + OFF_Wz2b;
  const u16* Wz3b = wsw + OFF_Wz3b;
  const u16* Wz1t = wsw + OFF_Wz1t;
  const u16* Wz2t = wsw + OFF_Wz2t;
  const u16* Wz3t = wsw + OFF_Wz3t;
  const u16* Wz0t = wsw + OFF_Wz0t;
  const u16* Wx2t = wsw + OFF_Wx2t;
  u64* slab0 = (u64*)(wsw + OFF_S0);
  u64* slab1 = (u64*)(wsw + OFF_S1);
  u64* slab2 = (u64*)(wsw + OFF_S2);

  // ---- stage x = state-1 into xbuf (bf16, padded row-major) ----
  {
    int r = tid >> 2, c0 = (tid & 3) << 4;
    const float* p = state + (blk * BM + r) * D + c0;
    u32* dst = (u32*)&xbuf[r * 72 + c0];
#pragma unroll
    for (int i = 0; i < 4; ++i) {
      f32x4 v = __builtin_nontemporal_load((const f32x4*)(p + i * 4));
      dst[i * 2]     = f2b(v[0] - 1.0f) | (f2b(v[1] - 1.0f) << 16);
      dst[i * 2 + 1] = f2b(v[2] - 1.0f) | (f2b(v[3] - 1.0f) << 16);
    }
  }

  f32x4 acc[4][8];
  const f32x4 Z = {0.f, 0.f, 0.f, 0.f};

  auto ldA = [&](int mt, int step) -> bf16x8 {     // LDS A-frag (swizzled)
    int m = mt * 16 + l15;
    int idx = m * H + (((step * 4 + q) ^ (m & 7)) << 3);
    return *(const bf16x8*)(&zbuf[idx]);
  };
  auto ldX = [&](int mt, int ks) -> bf16x8 {       // x A-frag from padded xbuf
    return *(const bf16x8*)(&xbuf[(mt * 16 + l15) * 72 + ks * 32 + q * 8]);
  };
  auto wrZ = [&](int row, int n, u16 bits) {       // swizzled LDS bf16 write
    zbuf[row * H + ((((n >> 3) ^ (row & 7))) << 3) + (n & 7)] = bits;
  };

  // acc (+)= x @ Wx^T (K=64). zero_first: overwrite acc on ks==0.
  auto fwdX = [&](const u16* Wxp, bool zero_first) {
    const u16* xb = Wxp + (w * 8) * 1024 + lane * 8;
#pragma unroll
    for (int ks = 0; ks < 2; ++ks) {
      bf16x8 ax[4];
#pragma unroll
      for (int mt = 0; mt < 4; ++mt) ax[mt] = ldX(mt, ks);
#pragma unroll
      for (int half = 0; half < 2; ++half) {
        bf16x8 b4[4];
#pragma unroll
        for (int nt = 0; nt < 4; ++nt)
          b4[nt] = *(const bf16x8*)(xb + (half * 4 + nt) * 1024 + ks * 512);
#pragma unroll
        for (int nt = 0; nt < 4; ++nt)
#pragma unroll
          for (int mt = 0; mt < 4; ++mt) {
            f32x4 c = (zero_first && ks == 0) ? Z : acc[mt][half * 4 + nt];
            acc[mt][half * 4 + nt] =
                __builtin_amdgcn_mfma_f32_16x16x32_bf16(ax[mt], b4[nt], c, 0, 0, 0);
          }
      }
    }
  };

  // acc = zbuf @ W^T (K=512), zero-start. Depth-2 full-step pipeline:
  // b0/b1 hold steps st and st+1; after consuming st, refill with st+2.
  auto fwdH = [&](const u16* Wp) {
    const u16* wb = Wp + (w * 8) * 8192 + lane * 8;
    bf16x8 b0[8], b1[8];
#pragma unroll
    for (int nt = 0; nt < 8; ++nt) b0[nt] = *(const bf16x8*)(wb + nt * 8192);
#pragma unroll
    for (int nt = 0; nt < 8; ++nt) b1[nt] = *(const bf16x8*)(wb + nt * 8192 + 512);
#pragma unroll
    for (int st = 0; st < 16; ++st) {
      bf16x8 a[4];
#pragma unroll
      for (int mt = 0; mt < 4; ++mt) a[mt] = ldA(mt, st);
#pragma unroll
      for (int nt = 0; nt < 8; ++nt) {
#pragma unroll
        for (int mt = 0; mt < 4; ++mt)
          acc[mt][nt] = __builtin_amdgcn_mfma_f32_16x16x32_bf16(
              a[mt], (st & 1) ? b1[nt] : b0[nt],
              (st == 0) ? Z : acc[mt][nt], 0, 0, 0);
      }
      if (st < 14) {
        int sn = st + 2;
#pragma unroll
        for (int nt = 0; nt < 8; ++nt) {
          bf16x8 v = *(const bf16x8*)(wb + nt * 8192 + sn * 512);
          if (st & 1) b1[nt] = v; else b0[nt] = v;
        }
      }
    }
  };

  // forward epilogue: a+=bias; z=softplus -> zbuf; s=sigmoid -> slab
  auto fwd_epi = [&](const float* biasp, u64* slab) {
    float bias[8];
#pragma unroll
    for (int nt = 0; nt < 8; ++nt) bias[nt] = biasp[w * 128 + nt * 16 + l15];
#pragma unroll
    for (int mt = 0; mt < 4; ++mt)
#pragma unroll
      for (int nt = 0; nt < 8; ++nt) {
        int n = w * 128 + nt * 16 + l15;
        f32x4 A = acc[mt][nt];
        u64 pack = 0;
#pragma unroll
        for (int r = 0; r < 4; ++r) {
          float a = A[r] + bias[nt];
          float t = __expf(-a);
          float u = 1.0f + t;
          float s = __builtin_amdgcn_rcpf(u);     // sigmoid(a)
          float z = a + __logf(u);                // softplus(a)
          pack |= (u64)f2b(s) << (16 * r);
          wrZ(mt * 16 + q * 4 + r, n, (u16)f2b(z));
        }
        slab[(blk4w * 32 + mt * 8 + nt) * 64 + lane] = pack;
      }
  };
  auto d3_epi = [&](const float* biasp) {   // d3 = WzL * sigmoid(a3) -> zbuf
    float bias[8], wl[8];
#pragma unroll
    for (int nt = 0; nt < 8; ++nt) {
      bias[nt] = biasp[w * 128 + nt * 16 + l15];
      wl[nt] = WzL[w * 128 + nt * 16 + l15];
    }
#pragma unroll
    for (int mt = 0; mt < 4; ++mt)
#pragma unroll
      for (int nt = 0; nt < 8; ++nt) {
        int n = w * 128 + nt * 16 + l15;
        f32x4 A = acc[mt][nt];
#pragma unroll
        for (int r = 0; r < 4; ++r) {
          float a = A[r] + bias[nt];
          float t = __expf(-a);
          float s = __builtin_amdgcn_rcpf(1.0f + t);
          wrZ(mt * 16 + q * 4 + r, n, (u16)f2b(wl[nt] * s));
        }
      }
  };
  // d = g * s -> zbuf; optionally overwrite slab with d (for grad_kernel).
  // All 32 slab loads issued upfront (MLP).
  auto bwd_epi = [&](u64* slab, bool store_d) {
    u64 v[4][8];
#pragma unroll
    for (int mt = 0; mt < 4; ++mt)
#pragma unroll
      for (int nt = 0; nt < 8; ++nt)
        v[mt][nt] = slab[(blk4w * 32 + mt * 8 + nt) * 64 + lane];
#pragma unroll
    for (int mt = 0; mt < 4; ++mt)
#pragma unroll
      for (int nt = 0; nt < 8; ++nt) {
        int n = w * 128 + nt * 16 + l15;
        f32x4 A = acc[mt][nt];
        u64 pack = 0;
#pragma unroll
        for (int r = 0; r < 4; ++r) {
          float s = b2f((u32)(v[mt][nt] >> (16 * r)) & 0xffffu);
          u32 db = f2b(A[r] * s);
          pack |= (u64)db << (16 * r);
          wrZ(mt * 16 + q * 4 + r, n, (u16)db);
        }
        if (store_d)
          slab[(blk4w * 32 + mt * 8 + nt) * 64 + lane] = pack;
      }
  };

  // ---------------- forward ----------------
  __syncthreads();                          // xbuf ready
  fwdX(Wz0b, true);                         // a0 = x@Wz0^T
  __syncthreads(); fwd_epi(bz0, slab0); __syncthreads();
  fwdH(Wz1b); fwdX(Wx0b, false);            // a1 = z0@Wz1^T + x@Wx0^T
  __syncthreads(); fwd_epi(bx0, slab1); __syncthreads();
  fwdH(Wz2b); fwdX(Wx1b, false);
  __syncthreads(); fwd_epi(bx1, slab2); __syncthreads();
  fwdH(Wz3b); fwdX(Wx2b, false);
  __syncthreads(); d3_epi(bx2); __syncthreads();
  // ---- mini-phase: t3 = d3 @ Wx2t (grad cols w*16+l15), parked bf16 in xb64.
  // acc is dead here: load ALL 16 g-frags upfront (one latency exposure).
  {
    const u16* gb = Wx2t + (w * 16) * 512 + lane * 8;
    bf16x8 g[16];
#pragma unroll
    for (int st = 0; st < 16; ++st) g[st] = *(const bf16x8*)(gb + st * 512);
    f32x4 t3[4];
#pragma unroll
    for (int mt = 0; mt < 4; ++mt) t3[mt] = Z;
#pragma unroll
    for (int st = 0; st < 16; ++st) {
      bf16x8 a[4];
#pragma unroll
      for (int mt = 0; mt < 4; ++mt) a[mt] = ldA(mt, st);
#pragma unroll
      for (int mt = 0; mt < 4; ++mt)
        t3[mt] = __builtin_amdgcn_mfma_f32_16x16x32_bf16(a[mt], g[st], t3[mt], 0, 0, 0);
    }
#pragma unroll
    for (int mt = 0; mt < 4; ++mt) {
      u64 pack = 0;
#pragma unroll
      for (int r = 0; r < 4; ++r) pack |= (u64)f2b(t3[mt][r]) << (16 * r);
      xb64[(w * 4 + mt) * 64 + lane] = pack;  // wave-private park
    }
  }
  // ---------------- backward (Wz chain only) ----------------
  fwdH(Wz3t);                               // g2 = d3@Wz3
  __syncthreads(); bwd_epi(slab2, true);  __syncthreads();   // d2 -> zbuf + slab2
  fwdH(Wz2t);
  __syncthreads(); bwd_epi(slab1, true);  __syncthreads();   // d1 -> zbuf + slab1
  fwdH(Wz1t);
  __syncthreads(); bwd_epi(slab0, false); __syncthreads();   // d0 -> zbuf only
  // ---- final: gacc = d0@Wz0t; out = gacc + WxL + t3 (g-frags upfront) ----
  {
    const u16* gb = Wz0t + (w * 16) * 512 + lane * 8;
    bf16x8 g[16];
#pragma unroll
    for (int st = 0; st < 16; ++st) g[st] = *(const bf16x8*)(gb + st * 512);
    f32x4 gacc[4];
#pragma unroll
    for (int mt = 0; mt < 4; ++mt) gacc[mt] = Z;
#pragma unroll
    for (int st = 0; st < 16; ++st) {
      bf16x8 a[4];
#pragma unroll
      for (int mt = 0; mt < 4; ++mt) a[mt] = ldA(mt, st);
#pragma unroll
      for (int mt = 0; mt < 4; ++mt)
        gacc[mt] = __builtin_amdgcn_mfma_f32_16x16x32_bf16(a[mt], g[st], gacc[mt], 0, 0, 0);
    }
    int n2 = w * 16 + l15;
    float wx = WxL[n2];
#pragma unroll
    for (int mt = 0; mt < 4; ++mt) {
      u64 tv = xb64[(w * 4 + mt) * 64 + lane];
#pragma unroll
      for (int r = 0; r < 4; ++r)
        out[(blk * BM + mt * 16 + q * 4 + r) * D + n2] =
            gacc[mt][r] + wx + b2f((u32)(tv >> (16 * r)) & 0xffffu);
    }
  }
}

// ---- grad finisher: out += d1@Wx0t + d2@Wx1t (slabs hold d1/d2) ----
__global__ __launch_bounds__(256, 2) void grad_kernel(
    const u16* __restrict__ wsw, float* __restrict__ out) {
  __shared__ u16 zbuf[BM * H];
  const int tid = threadIdx.x;
  const int w = tid >> 6;
  const int lane = tid & 63;
  const int l15 = lane & 15;
  const int q = lane >> 4;
  const int blk = blockIdx.x;
  const int blk4w = blk * 4 + w;

  auto ldA = [&](int mt, int step) -> bf16x8 {
    int m = mt * 16 + l15;
    int idx = m * H + (((step * 4 + q) ^ (m & 7)) << 3);
    return *(const bf16x8*)(&zbuf[idx]);
  };
  auto wrZ = [&](int row, int n, u16 bits) {
    zbuf[row * H + ((((n >> 3) ^ (row & 7))) << 3) + (n & 7)] = bits;
  };

  f32x4 gacc[4];
  const f32x4 Z = {0.f, 0.f, 0.f, 0.f};
#pragma unroll
  for (int mt = 0; mt < 4; ++mt) gacc[mt] = Z;

  for (int pass = 0; pass < 2; ++pass) {
    const u64* slab = (const u64*)(wsw + (pass ? OFF_S2 : OFF_S1));
    const u16* Wg = wsw + (pass ? OFF_Wx1t : OFF_Wx0t);
    __syncthreads();                       // zbuf free (prev pass reads done)
    u64 v[4][8];
#pragma unroll
    for (int mt = 0; mt < 4; ++mt)
#pragma unroll
      for (int nt = 0; nt < 8; ++nt)
        v[mt][nt] = slab[(blk4w * 32 + mt * 8 + nt) * 64 + lane];
    const u16* gb = Wg + (w * 16) * 512 + lane * 8;
    bf16x8 g[16];
#pragma unroll
    for (int st = 0; st < 16; ++st) g[st] = *(const bf16x8*)(gb + st * 512);
#pragma unroll
    for (int mt = 0; mt < 4; ++mt)
#pragma unroll
      for (int nt = 0; nt < 8; ++nt) {
        int n = w * 128 + nt * 16 + l15;
#pragma unroll
        for (int r = 0; r < 4; ++r)
          wrZ(mt * 16 + q * 4 + r, n, (u16)((v[mt][nt] >> (16 * r)) & 0xffffu));
      }
    __syncthreads();
#pragma unroll
    for (int st = 0; st < 16; ++st) {
      bf16x8 a[4];
#pragma unroll
      for (int mt = 0; mt < 4; ++mt) a[mt] = ldA(mt, st);
#pragma unroll
      for (int mt = 0; mt < 4; ++mt)
        gacc[mt] = __builtin_amdgcn_mfma_f32_16x16x32_bf16(a[mt], g[st], gacc[mt], 0, 0, 0);
    }
  }
  int n2 = w * 16 + l15;
#pragma unroll
  for (int mt = 0; mt < 4; ++mt)
#pragma unroll
    for (int r = 0; r < 4; ++r) {
      float* p = &out[(blk * BM + mt * 16 + q * 4 + r) * D + n2];
      *p += gacc[mt][r];
    }
}

extern "C" void kernel_launch(void* const* d_in, const int* in_sizes, int n_in,
                              void* d_out, int out_size, void* d_ws, size_t ws_size,
                              hipStream_t stream) {
  const float* state = (const float*)d_in[0];
  const float* Wz0 = (const float*)d_in[1];
  const float* bz0 = (const float*)d_in[2];
  const float* Wz1 = (const float*)d_in[3];
  const float* Wz2 = (const float*)d_in[4];
  const float* Wz3 = (const float*)d_in[5];
  const float* WzL = (const float*)d_in[6];
  const float* Wx0 = (const float*)d_in[7];
  const float* bx0 = (const float*)d_in[8];
  const float* Wx1 = (const float*)d_in[9];
  const float* bx1 = (const float*)d_in[10];
  const float* Wx2 = (const float*)d_in[11];
  const float* bx2 = (const float*)d_in[12];
  const float* WxL = (const float*)d_in[13];

  if (ws_size < (size_t)WS_ELEMS * 2) {
    fill_sentinel<<<(out_size + 255) / 256, 256, 0, stream>>>((float*)d_out, out_size);
    return;
  }
  u16* wsw = (u16*)d_ws;
  prep_kernel<<<OFF_WEND / 256, 256, 0, stream>>>(Wz0, Wz1, Wz2, Wz3, Wx0, Wx1, Wx2, wsw);
  icnn_kernel<<<B_TOTAL / BM, 256, 0, stream>>>(state, bz0, bx0, bx1, bx2, WzL, WxL,
                                                wsw, (float*)d_out);
  grad_kernel<<<B_TOTAL / BM, 256, 0, stream>>>(wsw, (float*)d_out);
}

// Round 9
// 660.137 us; speedup vs baseline: 1.5729x; 1.5729x over previous
//
#include <hip/hip_runtime.h>

typedef unsigned short u16;
typedef unsigned int u32;
typedef unsigned long long u64;

#define B_TOTAL 65536
#define H 512
#define D 64
#define BM 64

typedef __bf16 bf16x8 __attribute__((ext_vector_type(8)));
typedef float f32x4 __attribute__((ext_vector_type(4)));

__device__ __forceinline__ u32 f2b(float f) {  // fp32 -> bf16 bits, RNE
  u32 u = __builtin_bit_cast(u32, f);
  return (u + 0x7fffu + ((u >> 16) & 1u)) >> 16;
}
__device__ __forceinline__ float b2f(u32 bits) {
  return __builtin_bit_cast(float, bits << 16);
}

// ---- workspace layout (bf16 element offsets) ----
// Weight regions are FRAGMENT-PACKED: for logical B-matrix M[NN][KK],
// packed[( (n>>4)*(KK/32) + (k>>5) )*512 + lane*8 + j] = M[n][k],
// n = ntile*16 + (lane&15), k = kstep*32 + (lane>>4)*8 + j.
#define OFF_Wz0b 0          /* [N=512][K=64]  fwd L0 */
#define OFF_Wx0b 32768
#define OFF_Wx1b 65536
#define OFF_Wx2b 98304
#define OFF_Wz1b 131072     /* [N=512][K=512] fwd */
#define OFF_Wz2b 393216
#define OFF_Wz3b 655360
#define OFF_Wz1t 917504     /* [N=512][K=512] transposed, bwd */
#define OFF_Wz2t 1179648
#define OFF_Wz3t 1441792
#define OFF_Wz0t 1703936    /* [N=64][K=512] transposed grad weights */
#define OFF_Wx0t 1736704
#define OFF_Wx1t 1769472
#define OFF_Wx2t 1802240
#define OFF_WEND 1835008
#define SLAB_ELEMS (B_TOTAL * H)          /* 33,554,432 bf16 per slab */
#define OFF_S0 OFF_WEND
#define OFF_S1 (OFF_S0 + SLAB_ELEMS)
#define OFF_S2 (OFF_S1 + SLAB_ELEMS)
#define WS_ELEMS (OFF_S2 + SLAB_ELEMS)    /* ~102.5M elems = ~205 MB */

// ---- weight prep: fp32 -> bf16, fragment-packed (+ transposed variants) ----
__global__ __launch_bounds__(256) void prep_kernel(
    const float* __restrict__ Wz0, const float* __restrict__ Wz1,
    const float* __restrict__ Wz2, const float* __restrict__ Wz3,
    const float* __restrict__ Wx0, const float* __restrict__ Wx1,
    const float* __restrict__ Wx2, u16* __restrict__ wsb) {
  int i = blockIdx.x * 256 + threadIdx.x;   // grid exactly covers OFF_WEND
  const float* src;
  int NN, KK, trans, p;
  if (i < 131072) {                          // x-path fwd: [512][64] direct
    int r = i >> 15; p = i & 32767;
    src = (r == 0) ? Wz0 : (r == 1) ? Wx0 : (r == 2) ? Wx1 : Wx2;
    NN = 512; KK = 64; trans = 0;
  } else if (i < 917504) {                   // H fwd: [512][512] direct
    int j = i - 131072; int r = j >> 18; p = j & 262143;
    src = (r == 0) ? Wz1 : (r == 1) ? Wz2 : Wz3;
    NN = 512; KK = 512; trans = 0;
  } else if (i < 1703936) {                  // H bwd: transposed
    int j = i - 917504; int r = j >> 18; p = j & 262143;
    src = (r == 0) ? Wz1 : (r == 1) ? Wz2 : Wz3;
    NN = 512; KK = 512; trans = 1;
  } else {                                   // grad weights: [64][512] = W^T
    int j = i - 1703936; int r = j >> 15; p = j & 32767;
    src = (r == 0) ? Wz0 : (r == 1) ? Wx0 : (r == 2) ? Wx1 : Wx2;
    NN = 64; KK = 512; trans = 1;
  }
  int jj = p & 7, lane = (p >> 3) & 63, blk = p >> 9;
  int kt_sh = (KK == 64) ? 1 : 4;            // log2(KK/32)
  int ntile = blk >> kt_sh;
  int kstep = blk & ((1 << kt_sh) - 1);
  int n = ntile * 16 + (lane & 15);
  int k = kstep * 32 + ((lane >> 4) << 3) + jj;
  float v = trans ? src[k * NN + n] : src[n * KK + k];
  wsb[i] = (u16)f2b(v);
}

__global__ __launch_bounds__(256) void fill_sentinel(float* out, int n) {
  int i = blockIdx.x * 256 + threadIdx.x;
  if (i < n) out[i] = 12345.0f;   // unmistakable "workspace too small" marker
}

// ---- fused ICNN fwd + bwd-through-Wz; grad side-terms split out ----
// R9: fwdH weights flow global->LDS via __builtin_amdgcn_global_load_lds
// (width=16, fire-and-forget DMA) into a double-buffered 2x32 KB wbuf.
// Each wave stages and reads ONLY its own 8 KB chunk region -> no per-step
// barrier; wave-local `s_waitcnt vmcnt(8)` (inline asm, memory clobber)
// waits for the PREVIOUS step's 8 DMAs while this step's 8 fly (AITER
// pattern, never vmcnt(0) mid-loop). Step-0 prestaged during the preceding
// epilogue. LDS 137 KB -> 1 block/CU; launch_bounds(256,1) -> 512-VGPR budget.
__global__ __launch_bounds__(256, 1) void icnn_kernel(
    const float* __restrict__ state,
    const float* __restrict__ bz0, const float* __restrict__ bx0,
    const float* __restrict__ bx1, const float* __restrict__ bx2,
    const float* __restrict__ WzL, const float* __restrict__ WxL,
    u16* __restrict__ wsw, float* __restrict__ out) {
  __shared__ u16 zbuf[BM * H];      // XOR-swizzled activations, 64 KB
  __shared__ u16 wbuf[2 * 16384];   // double-buffered weight K-slices, 64 KB
  // x staging needs BM*72 u16 = 9216 B; t3 park needs 1024 u64 = 8192 B.
  __shared__ u64 xb64[BM * 18];
  u16* xbuf = (u16*)xb64;

  const int tid = threadIdx.x;
  const int w = tid >> 6;
  const int lane = tid & 63;
  const int l15 = lane & 15;
  const int q = lane >> 4;
  const int blk = blockIdx.x;
  const int blk4w = blk * 4 + w;

  const u16* Wz0b = wsw + OFF_Wz0b;
  const u16* Wx0b = wsw + OFF_Wx0b;
  const u16* Wx1b = wsw + OFF_Wx1b;
  const u16* Wx2b = wsw + OFF_Wx2b;
  const u16* Wz1b = wsw + OFF_Wz1b;
  const u16* Wz2b = wsw + OFF_Wz2b;
  const u16* Wz3b = wsw + OFF_Wz3b;
  const u16* Wz1t = wsw + OFF_Wz1t;
  const u16* Wz2t = wsw + OFF_Wz2t;
  const u16* Wz3t = wsw + OFF_Wz3t;
  const u16* Wz0t = wsw + OFF_Wz0t;
  const u16* Wx2t = wsw + OFF_Wx2t;
  u64* slab0 = (u64*)(wsw + OFF_S0);
  u64* slab1 = (u64*)(wsw + OFF_S1);
  u64* slab2 = (u64*)(wsw + OFF_S2);

  // ---- stage x = state-1 into xbuf (bf16, padded row-major) ----
  {
    int r = tid >> 2, c0 = (tid & 3) << 4;
    const float* p = state + (blk * BM + r) * D + c0;
    u32* dst = (u32*)&xbuf[r * 72 + c0];
#pragma unroll
    for (int i = 0; i < 4; ++i) {
      f32x4 v = __builtin_nontemporal_load((const f32x4*)(p + i * 4));
      dst[i * 2]     = f2b(v[0] - 1.0f) | (f2b(v[1] - 1.0f) << 16);
      dst[i * 2 + 1] = f2b(v[2] - 1.0f) | (f2b(v[3] - 1.0f) << 16);
    }
  }

  f32x4 acc[4][8];
  const f32x4 Z = {0.f, 0.f, 0.f, 0.f};

  auto ldA = [&](int mt, int step) -> bf16x8 {     // LDS A-frag (swizzled)
    int m = mt * 16 + l15;
    int idx = m * H + (((step * 4 + q) ^ (m & 7)) << 3);
    return *(const bf16x8*)(&zbuf[idx]);
  };
  auto ldX = [&](int mt, int ks) -> bf16x8 {       // x A-frag from padded xbuf
    return *(const bf16x8*)(&xbuf[(mt * 16 + l15) * 72 + ks * 32 + q * 8]);
  };
  auto wrZ = [&](int row, int n, u16 bits) {       // swizzled LDS bf16 write
    zbuf[row * H + ((((n >> 3) ^ (row & 7))) << 3) + (n & 7)] = bits;
  };

  // DMA one K-step slice (this wave's 8 chunks, 8 KB) into wbuf[buf].
  // Lane i's 16 B land at lds_base + i*16 (HW rule) == packed order.
  auto stageW = [&](const u16* Wp, int st, int buf) {
    const u16* gb = Wp + (w * 8 * 16 + st) * 512 + lane * 8;
    u16* lb = &wbuf[buf * 16384 + (w * 8) * 512];
#pragma unroll
    for (int j = 0; j < 8; ++j)
      __builtin_amdgcn_global_load_lds(
          (const __attribute__((address_space(1))) void*)(gb + j * 16 * 512),
          (__attribute__((address_space(3))) void*)(lb + j * 512), 16, 0, 0);
  };

  // acc (+)= x @ Wx^T (K=64). zero_first: overwrite acc on ks==0.
  auto fwdX = [&](const u16* Wxp, bool zero_first) {
    const u16* xb = Wxp + (w * 8) * 1024 + lane * 8;
#pragma unroll
    for (int ks = 0; ks < 2; ++ks) {
      bf16x8 ax[4];
#pragma unroll
      for (int mt = 0; mt < 4; ++mt) ax[mt] = ldX(mt, ks);
#pragma unroll
      for (int half = 0; half < 2; ++half) {
        bf16x8 b4[4];
#pragma unroll
        for (int nt = 0; nt < 4; ++nt)
          b4[nt] = *(const bf16x8*)(xb + (half * 4 + nt) * 1024 + ks * 512);
#pragma unroll
        for (int nt = 0; nt < 4; ++nt)
#pragma unroll
          for (int mt = 0; mt < 4; ++mt) {
            f32x4 c = (zero_first && ks == 0) ? Z : acc[mt][half * 4 + nt];
            acc[mt][half * 4 + nt] =
                __builtin_amdgcn_mfma_f32_16x16x32_bf16(ax[mt], b4[nt], c, 0, 0, 0);
          }
      }
    }
  };

  // acc = zbuf @ W^T (K=512), zero-start. Contract: step 0 already staged
  // into wbuf[0] (8 DMAs in flight or complete) by the caller.
  auto fwdH = [&](const u16* Wp) {
#pragma unroll
    for (int st = 0; st < 16; ++st) {
      if (st < 15) {
        stageW(Wp, st + 1, (st + 1) & 1);
        asm volatile("s_waitcnt vmcnt(8)" ::: "memory");  // prev step's 8 DMAs done
      } else {
        asm volatile("s_waitcnt vmcnt(0)" ::: "memory");
      }
      const u16* wb = &wbuf[(st & 1) * 16384 + (w * 8) * 512 + lane * 8];
      bf16x8 a[4];
#pragma unroll
      for (int mt = 0; mt < 4; ++mt) a[mt] = ldA(mt, st);
#pragma unroll
      for (int nt = 0; nt < 8; ++nt) {
        bf16x8 b = *(const bf16x8*)(wb + nt * 512);
#pragma unroll
        for (int mt = 0; mt < 4; ++mt)
          acc[mt][nt] = __builtin_amdgcn_mfma_f32_16x16x32_bf16(
              a[mt], b, (st == 0) ? Z : acc[mt][nt], 0, 0, 0);
      }
    }
  };

  // forward epilogue: a+=bias; z=softplus -> zbuf; s=sigmoid -> slab
  auto fwd_epi = [&](const float* biasp, u64* slab) {
    float bias[8];
#pragma unroll
    for (int nt = 0; nt < 8; ++nt) bias[nt] = biasp[w * 128 + nt * 16 + l15];
#pragma unroll
    for (int mt = 0; mt < 4; ++mt)
#pragma unroll
      for (int nt = 0; nt < 8; ++nt) {
        int n = w * 128 + nt * 16 + l15;
        f32x4 A = acc[mt][nt];
        u64 pack = 0;
#pragma unroll
        for (int r = 0; r < 4; ++r) {
          float a = A[r] + bias[nt];
          float t = __expf(-a);
          float u = 1.0f + t;
          float s = __builtin_amdgcn_rcpf(u);     // sigmoid(a)
          float z = a + __logf(u);                // softplus(a)
          pack |= (u64)f2b(s) << (16 * r);
          wrZ(mt * 16 + q * 4 + r, n, (u16)f2b(z));
        }
        slab[(blk4w * 32 + mt * 8 + nt) * 64 + lane] = pack;
      }
  };
  auto d3_epi = [&](const float* biasp) {   // d3 = WzL * sigmoid(a3) -> zbuf
    float bias[8], wl[8];
#pragma unroll
    for (int nt = 0; nt < 8; ++nt) {
      bias[nt] = biasp[w * 128 + nt * 16 + l15];
      wl[nt] = WzL[w * 128 + nt * 16 + l15];
    }
#pragma unroll
    for (int mt = 0; mt < 4; ++mt)
#pragma unroll
      for (int nt = 0; nt < 8; ++nt) {
        int n = w * 128 + nt * 16 + l15;
        f32x4 A = acc[mt][nt];
#pragma unroll
        for (int r = 0; r < 4; ++r) {
          float a = A[r] + bias[nt];
          float t = __expf(-a);
          float s = __builtin_amdgcn_rcpf(1.0f + t);
          wrZ(mt * 16 + q * 4 + r, n, (u16)f2b(wl[nt] * s));
        }
      }
  };
  // d = g * s -> zbuf; optionally overwrite slab with d (for grad_kernel)
  auto bwd_epi = [&](u64* slab, bool store_d) {
    u64 v[4][8];
#pragma unroll
    for (int mt = 0; mt < 4; ++mt)
#pragma unroll
      for (int nt = 0; nt < 8; ++nt)
        v[mt][nt] = slab[(blk4w * 32 + mt * 8 + nt) * 64 + lane];
#pragma unroll
    for (int mt = 0; mt < 4; ++mt)
#pragma unroll
      for (int nt = 0; nt < 8; ++nt) {
        int n = w * 128 + nt * 16 + l15;
        f32x4 A = acc[mt][nt];
        u64 pack = 0;
#pragma unroll
        for (int r = 0; r < 4; ++r) {
          float s = b2f((u32)(v[mt][nt] >> (16 * r)) & 0xffffu);
          u32 db = f2b(A[r] * s);
          pack |= (u64)db << (16 * r);
          wrZ(mt * 16 + q * 4 + r, n, (u16)db);
        }
        if (store_d)
          slab[(blk4w * 32 + mt * 8 + nt) * 64 + lane] = pack;
      }
  };

  // ---------------- forward ----------------
  __syncthreads();                          // xbuf ready
  fwdX(Wz0b, true);                         // a0 = x@Wz0^T
  __syncthreads();
  stageW(Wz1b, 0, 0);                       // prestage; overlaps epilogue
  fwd_epi(bz0, slab0);
  __syncthreads();
  fwdH(Wz1b); fwdX(Wx0b, false);            // a1 = z0@Wz1^T + x@Wx0^T
  __syncthreads();
  stageW(Wz2b, 0, 0);
  fwd_epi(bx0, slab1);
  __syncthreads();
  fwdH(Wz2b); fwdX(Wx1b, false);
  __syncthreads();
  stageW(Wz3b, 0, 0);
  fwd_epi(bx1, slab2);
  __syncthreads();
  fwdH(Wz3b); fwdX(Wx2b, false);
  __syncthreads();
  stageW(Wz3t, 0, 0);                       // prestage bwd; overlaps d3_epi + mini
  d3_epi(bx2);
  __syncthreads();
  // ---- mini-phase: t3 = d3 @ Wx2t (grad cols w*16+l15), parked in xb64 ----
  {
    const u16* gb = Wx2t + (w * 16) * 512 + lane * 8;
    bf16x8 g[16];
#pragma unroll
    for (int st = 0; st < 16; ++st) g[st] = *(const bf16x8*)(gb + st * 512);
    f32x4 t3[4];
#pragma unroll
    for (int mt = 0; mt < 4; ++mt) t3[mt] = Z;
#pragma unroll
    for (int st = 0; st < 16; ++st) {
      bf16x8 a[4];
#pragma unroll
      for (int mt = 0; mt < 4; ++mt) a[mt] = ldA(mt, st);
#pragma unroll
      for (int mt = 0; mt < 4; ++mt)
        t3[mt] = __builtin_amdgcn_mfma_f32_16x16x32_bf16(a[mt], g[st], t3[mt], 0, 0, 0);
    }
#pragma unroll
    for (int mt = 0; mt < 4; ++mt) {
      u64 pack = 0;
#pragma unroll
      for (int r = 0; r < 4; ++r) pack |= (u64)f2b(t3[mt][r]) << (16 * r);
      xb64[(w * 4 + mt) * 64 + lane] = pack;  // wave-private park
    }
  }
  // ---------------- backward (Wz chain only) ----------------
  fwdH(Wz3t);                               // g2 = d3@Wz3
  __syncthreads();
  stageW(Wz2t, 0, 0);
  bwd_epi(slab2, true);                     // d2 -> zbuf + slab2
  __syncthreads();
  fwdH(Wz2t);
  __syncthreads();
  stageW(Wz1t, 0, 0);
  bwd_epi(slab1, true);                     // d1 -> zbuf + slab1
  __syncthreads();
  fwdH(Wz1t);
  __syncthreads();
  bwd_epi(slab0, false);                    // d0 -> zbuf only
  __syncthreads();
  // ---- final: gacc = d0@Wz0t; out = gacc + WxL + t3 (g-frags upfront) ----
  {
    const u16* gb = Wz0t + (w * 16) * 512 + lane * 8;
    bf16x8 g[16];
#pragma unroll
    for (int st = 0; st < 16; ++st) g[st] = *(const bf16x8*)(gb + st * 512);
    f32x4 gacc[4];
#pragma unroll
    for (int mt = 0; mt < 4; ++mt) gacc[mt] = Z;
#pragma unroll
    for (int st = 0; st < 16; ++st) {
      bf16x8 a[4];
#pragma unroll
      for (int mt = 0; mt < 4; ++mt) a[mt] = ldA(mt, st);
#pragma unroll
      for (int mt = 0; mt < 4; ++mt)
        gacc[mt] = __builtin_amdgcn_mfma_f32_16x16x32_bf16(a[mt], g[st], gacc[mt], 0, 0, 0);
    }
    int n2 = w * 16 + l15;
    float wx = WxL[n2];
#pragma unroll
    for (int mt = 0; mt < 4; ++mt) {
      u64 tv = xb64[(w * 4 + mt) * 64 + lane];
#pragma unroll
      for (int r = 0; r < 4; ++r)
        out[(blk * BM + mt * 16 + q * 4 + r) * D + n2] =
            gacc[mt][r] + wx + b2f((u32)(tv >> (16 * r)) & 0xffffu);
    }
  }
}

// ---- grad finisher: out += d1@Wx0t + d2@Wx1t (slabs hold d1/d2) ----
__global__ __launch_bounds__(256, 2) void grad_kernel(
    const u16* __restrict__ wsw, float* __restrict__ out) {
  __shared__ u16 zbuf[BM * H];
  const int tid = threadIdx.x;
  const int w = tid >> 6;
  const int lane = tid & 63;
  const int l15 = lane & 15;
  const int q = lane >> 4;
  const int blk = blockIdx.x;
  const int blk4w = blk * 4 + w;

  auto ldA = [&](int mt, int step) -> bf16x8 {
    int m = mt * 16 + l15;
    int idx = m * H + (((step * 4 + q) ^ (m & 7)) << 3);
    return *(const bf16x8*)(&zbuf[idx]);
  };
  auto wrZ = [&](int row, int n, u16 bits) {
    zbuf[row * H + ((((n >> 3) ^ (row & 7))) << 3) + (n & 7)] = bits;
  };

  f32x4 gacc[4];
  const f32x4 Z = {0.f, 0.f, 0.f, 0.f};
#pragma unroll
  for (int mt = 0; mt < 4; ++mt) gacc[mt] = Z;

  for (int pass = 0; pass < 2; ++pass) {
    const u64* slab = (const u64*)(wsw + (pass ? OFF_S2 : OFF_S1));
    const u16* Wg = wsw + (pass ? OFF_Wx1t : OFF_Wx0t);
    __syncthreads();                       // zbuf free (prev pass reads done)
    u64 v[4][8];
#pragma unroll
    for (int mt = 0; mt < 4; ++mt)
#pragma unroll
      for (int nt = 0; nt < 8; ++nt)
        v[mt][nt] = slab[(blk4w * 32 + mt * 8 + nt) * 64 + lane];
    const u16* gb = Wg + (w * 16) * 512 + lane * 8;
    bf16x8 g[16];
#pragma unroll
    for (int st = 0; st < 16; ++st) g[st] = *(const bf16x8*)(gb + st * 512);
#pragma unroll
    for (int mt = 0; mt < 4; ++mt)
#pragma unroll
      for (int nt = 0; nt < 8; ++nt) {
        int n = w * 128 + nt * 16 + l15;
#pragma unroll
        for (int r = 0; r < 4; ++r)
          wrZ(mt * 16 + q * 4 + r, n, (u16)((v[mt][nt] >> (16 * r)) & 0xffffu));
      }
    __syncthreads();
#pragma unroll
    for (int st = 0; st < 16; ++st) {
      bf16x8 a[4];
#pragma unroll
      for (int mt = 0; mt < 4; ++mt) a[mt] = ldA(mt, st);
#pragma unroll
      for (int mt = 0; mt < 4; ++mt)
        gacc[mt] = __builtin_amdgcn_mfma_f32_16x16x32_bf16(a[mt], g[st], gacc[mt], 0, 0, 0);
    }
  }
  int n2 = w * 16 + l15;
#pragma unroll
  for (int mt = 0; mt < 4; ++mt)
#pragma unroll
    for (int r = 0; r < 4; ++r) {
      float* p = &out[(blk * BM + mt * 16 + q * 4 + r) * D + n2];
      *p += gacc[mt][r];
    }
}

extern "C" void kernel_launch(void* const* d_in, const int* in_sizes, int n_in,
                              void* d_out, int out_size, void* d_ws, size_t ws_size,
                              hipStream_t stream) {
  const float* state = (const float*)d_in[0];
  const float* Wz0 = (const float*)d_in[1];
  const float* bz0 = (const float*)d_in[2];
  const float* Wz1 = (const float*)d_in[3];
  const float* Wz2 = (const float*)d_in[4];
  const float* Wz3 = (const float*)d_in[5];
  const float* WzL = (const float*)d_in[6];
  const float* Wx0 = (const float*)d_in[7];
  const float* bx0 = (const float*)d_in[8];
  const float* Wx1 = (const float*)d_in[9];
  const float* bx1 = (const float*)d_in[10];
  const float* Wx2 = (const float*)d_in[11];
  const float* bx2 = (const float*)d_in[12];
  const float* WxL = (const float*)d_in[13];

  if (ws_size < (size_t)WS_ELEMS * 2) {
    fill_sentinel<<<(out_size + 255) / 256, 256, 0, stream>>>((float*)d_out, out_size);
    return;
  }
  u16* wsw = (u16*)d_ws;
  prep_kernel<<<OFF_WEND / 256, 256, 0, stream>>>(Wz0, Wz1, Wz2, Wz3, Wx0, Wx1, Wx2, wsw);
  icnn_kernel<<<B_TOTAL / BM, 256, 0, stream>>>(state, bz0, bx0, bx1, bx2, WzL, WxL,
                                                wsw, (float*)d_out);
  grad_kernel<<<B_TOTAL / BM, 256, 0, stream>>>(wsw, (float*)d_out);
}

// Round 10
// 495.133 us; speedup vs baseline: 2.0971x; 1.3333x over previous
//
#include <hip/hip_runtime.h>

typedef unsigned short u16;
typedef unsigned int u32;
typedef unsigned long long u64;

#define B_TOTAL 65536
#define H 512
#define D 64
#define BM 64

typedef __bf16 bf16x8 __attribute__((ext_vector_type(8)));
typedef float f32x4 __attribute__((ext_vector_type(4)));

__device__ __forceinline__ u32 f2b(float f) {  // fp32 -> bf16 bits, RNE
  u32 u = __builtin_bit_cast(u32, f);
  return (u + 0x7fffu + ((u >> 16) & 1u)) >> 16;
}
__device__ __forceinline__ float b2f(u32 bits) {
  return __builtin_bit_cast(float, bits << 16);
}

// ---- workspace layout (bf16 element offsets) ----
// Weight regions are FRAGMENT-PACKED: for logical B-matrix M[NN][KK],
// packed[( (n>>4)*(KK/32) + (k>>5) )*512 + lane*8 + j] = M[n][k],
// n = ntile*16 + (lane&15), k = kstep*32 + (lane>>4)*8 + j.
#define OFF_Wz0b 0          /* [N=512][K=64]  fwd L0 */
#define OFF_Wx0b 32768
#define OFF_Wx1b 65536
#define OFF_Wx2b 98304
#define OFF_Wz1b 131072     /* [N=512][K=512] fwd */
#define OFF_Wz2b 393216
#define OFF_Wz3b 655360
#define OFF_Wz1t 917504     /* [N=512][K=512] transposed, bwd */
#define OFF_Wz2t 1179648
#define OFF_Wz3t 1441792
#define OFF_Wz0t 1703936    /* [N=64][K=512] transposed grad weights */
#define OFF_Wx0t 1736704
#define OFF_Wx1t 1769472
#define OFF_Wx2t 1802240
#define OFF_WEND 1835008
#define SLAB_ELEMS (B_TOTAL * H)          /* 33,554,432 bf16 per slab */
#define OFF_S0 OFF_WEND
#define OFF_S1 (OFF_S0 + SLAB_ELEMS)
#define OFF_S2 (OFF_S1 + SLAB_ELEMS)
#define WS_ELEMS (OFF_S2 + SLAB_ELEMS)    /* ~102.5M elems = ~205 MB */

// ---- weight prep: fp32 -> bf16, fragment-packed (+ transposed variants) ----
__global__ __launch_bounds__(256) void prep_kernel(
    const float* __restrict__ Wz0, const float* __restrict__ Wz1,
    const float* __restrict__ Wz2, const float* __restrict__ Wz3,
    const float* __restrict__ Wx0, const float* __restrict__ Wx1,
    const float* __restrict__ Wx2, u16* __restrict__ wsb) {
  int i = blockIdx.x * 256 + threadIdx.x;   // grid exactly covers OFF_WEND
  const float* src;
  int NN, KK, trans, p;
  if (i < 131072) {                          // x-path fwd: [512][64] direct
    int r = i >> 15; p = i & 32767;
    src = (r == 0) ? Wz0 : (r == 1) ? Wx0 : (r == 2) ? Wx1 : Wx2;
    NN = 512; KK = 64; trans = 0;
  } else if (i < 917504) {                   // H fwd: [512][512] direct
    int j = i - 131072; int r = j >> 18; p = j & 262143;
    src = (r == 0) ? Wz1 : (r == 1) ? Wz2 : Wz3;
    NN = 512; KK = 512; trans = 0;
  } else if (i < 1703936) {                  // H bwd: transposed
    int j = i - 917504; int r = j >> 18; p = j & 262143;
    src = (r == 0) ? Wz1 : (r == 1) ? Wz2 : Wz3;
    NN = 512; KK = 512; trans = 1;
  } else {                                   // grad weights: [64][512] = W^T
    int j = i - 1703936; int r = j >> 15; p = j & 32767;
    src = (r == 0) ? Wz0 : (r == 1) ? Wx0 : (r == 2) ? Wx1 : Wx2;
    NN = 64; KK = 512; trans = 1;
  }
  int jj = p & 7, lane = (p >> 3) & 63, blk = p >> 9;
  int kt_sh = (KK == 64) ? 1 : 4;            // log2(KK/32)
  int ntile = blk >> kt_sh;
  int kstep = blk & ((1 << kt_sh) - 1);
  int n = ntile * 16 + (lane & 15);
  int k = kstep * 32 + ((lane >> 4) << 3) + jj;
  float v = trans ? src[k * NN + n] : src[n * KK + k];
  wsb[i] = (u16)f2b(v);
}

__global__ __launch_bounds__(256) void fill_sentinel(float* out, int n) {
  int i = blockIdx.x * 256 + threadIdx.x;
  if (i < n) out[i] = 12345.0f;   // unmistakable "workspace too small" marker
}

// ---- fully-fused ICNN fwd+bwd (single GEMM kernel) ----
// 512 thr = 8 waves (2/SIMD for TLP), BM=64 rows; wave w owns cols
// [w*64,+64) of the [64,512] GEMMs (acc[4][4] = 64 AGPR).
// Weights DMA global->LDS (global_load_lds w=16) into double-buffered wbuf;
// per-wave `s_waitcnt vmcnt(4)` waits only the PREVIOUS step's 4 DMAs (AITER
// pattern). Grad side-terms (d_i @ Wx*t) run as mini-phases where acc is dead,
// accumulating in a fp32 LDS park (unioned with the dead x-staging buffer).
// No second kernel; slabs hold only sigmoids (written once, read once).
__global__ __launch_bounds__(512, 2) void icnn_kernel(
    const float* __restrict__ state,
    const float* __restrict__ bz0, const float* __restrict__ bx0,
    const float* __restrict__ bx1, const float* __restrict__ bx2,
    const float* __restrict__ WzL, const float* __restrict__ WxL,
    u16* __restrict__ wsw, float* __restrict__ out) {
  __shared__ u16 zbuf[BM * H];      // XOR-swizzled activations, 64 KB
  __shared__ u16 wbuf[2 * 16384];   // double-buffered weight K-slices, 64 KB
  __shared__ f32x4 park[16 * 64];   // 16 KB: x-staging early, fp32 grad park late
  u16* xbuf = (u16*)park;           // x staging needs 64*72 u16 = 9216 B

  const int tid = threadIdx.x;
  const int w = tid >> 6;           // 0..7
  const int lane = tid & 63;
  const int l15 = lane & 15;
  const int q = lane >> 4;
  const int blk = blockIdx.x;

  const u16* Wz0b = wsw + OFF_Wz0b;
  const u16* Wx0b = wsw + OFF_Wx0b;
  const u16* Wx1b = wsw + OFF_Wx1b;
  const u16* Wx2b = wsw + OFF_Wx2b;
  const u16* Wz1b = wsw + OFF_Wz1b;
  const u16* Wz2b = wsw + OFF_Wz2b;
  const u16* Wz3b = wsw + OFF_Wz3b;
  const u16* Wz1t = wsw + OFF_Wz1t;
  const u16* Wz2t = wsw + OFF_Wz2t;
  const u16* Wz3t = wsw + OFF_Wz3t;
  const u16* Wz0t = wsw + OFF_Wz0t;
  const u16* Wx0t = wsw + OFF_Wx0t;
  const u16* Wx1t = wsw + OFF_Wx1t;
  const u16* Wx2t = wsw + OFF_Wx2t;
  u64* slab0 = (u64*)(wsw + OFF_S0);
  u64* slab1 = (u64*)(wsw + OFF_S1);
  u64* slab2 = (u64*)(wsw + OFF_S2);

  // ---- stage x = state-1 into xbuf (bf16, padded row-major) ----
  {
    int r = tid >> 3, c0 = (tid & 7) << 3;   // 64 rows x 8 chunks of 8 floats
    const float* p = state + (blk * BM + r) * D + c0;
    f32x4 v0 = __builtin_nontemporal_load((const f32x4*)p);
    f32x4 v1 = __builtin_nontemporal_load((const f32x4*)(p + 4));
    u32* dst = (u32*)&xbuf[r * 72 + c0];
    dst[0] = f2b(v0[0] - 1.0f) | (f2b(v0[1] - 1.0f) << 16);
    dst[1] = f2b(v0[2] - 1.0f) | (f2b(v0[3] - 1.0f) << 16);
    dst[2] = f2b(v1[0] - 1.0f) | (f2b(v1[1] - 1.0f) << 16);
    dst[3] = f2b(v1[2] - 1.0f) | (f2b(v1[3] - 1.0f) << 16);
  }

  f32x4 acc[4][4];
  const f32x4 Z = {0.f, 0.f, 0.f, 0.f};

  auto ldA = [&](int mt, int step) -> bf16x8 {     // LDS A-frag (swizzled)
    int m = mt * 16 + l15;
    int idx = m * H + (((step * 4 + q) ^ (m & 7)) << 3);
    return *(const bf16x8*)(&zbuf[idx]);
  };
  auto ldX = [&](int mt, int ks) -> bf16x8 {       // x A-frag from padded xbuf
    return *(const bf16x8*)(&xbuf[(mt * 16 + l15) * 72 + ks * 32 + q * 8]);
  };
  auto wrZ = [&](int row, int n, u16 bits) {       // swizzled LDS bf16 write
    zbuf[row * H + ((((n >> 3) ^ (row & 7))) << 3) + (n & 7)] = bits;
  };

  // DMA one K-step slice (this wave's 4 chunks, 4 KB) into wbuf[buf].
  auto stageW = [&](const u16* Wp, int st, int buf) {
    const u16* gb = Wp + (w * 4 * 16 + st) * 512 + lane * 8;
    u16* lb = &wbuf[buf * 16384 + (w * 4) * 512];
#pragma unroll
    for (int j = 0; j < 4; ++j)
      __builtin_amdgcn_global_load_lds(
          (const __attribute__((address_space(1))) void*)(gb + j * 16 * 512),
          (__attribute__((address_space(3))) void*)(lb + j * 512), 16, 0, 0);
  };

  // acc (+)= x @ Wx^T (K=64). zero_first: overwrite acc on ks==0.
  auto fwdX = [&](const u16* Wxp, bool zero_first) {
    const u16* xb = Wxp + lane * 8;
#pragma unroll
    for (int ks = 0; ks < 2; ++ks) {
      bf16x8 ax[4];
#pragma unroll
      for (int mt = 0; mt < 4; ++mt) ax[mt] = ldX(mt, ks);
      bf16x8 b4[4];
#pragma unroll
      for (int nt = 0; nt < 4; ++nt)
        b4[nt] = *(const bf16x8*)(xb + ((w * 4 + nt) * 2 + ks) * 512);
#pragma unroll
      for (int nt = 0; nt < 4; ++nt)
#pragma unroll
        for (int mt = 0; mt < 4; ++mt) {
          f32x4 c = (zero_first && ks == 0) ? Z : acc[mt][nt];
          acc[mt][nt] = __builtin_amdgcn_mfma_f32_16x16x32_bf16(ax[mt], b4[nt], c, 0, 0, 0);
        }
    }
  };

  // acc = zbuf @ W^T (K=512), zero-start. Contract: step 0 already staged
  // into wbuf[0] by the caller (before any intervening vmem loads are consumed).
  auto fwdH = [&](const u16* Wp) {
#pragma unroll
    for (int st = 0; st < 16; ++st) {
      if (st < 15) {
        stageW(Wp, st + 1, (st + 1) & 1);
        asm volatile("s_waitcnt vmcnt(4)" ::: "memory");  // prev step's 4 DMAs done
      } else {
        asm volatile("s_waitcnt vmcnt(0)" ::: "memory");
      }
      const u16* wb = &wbuf[(st & 1) * 16384 + (w * 4) * 512 + lane * 8];
      bf16x8 a[4];
#pragma unroll
      for (int mt = 0; mt < 4; ++mt) a[mt] = ldA(mt, st);
#pragma unroll
      for (int nt = 0; nt < 4; ++nt) {
        bf16x8 b = *(const bf16x8*)(wb + nt * 512);
#pragma unroll
        for (int mt = 0; mt < 4; ++mt)
          acc[mt][nt] = __builtin_amdgcn_mfma_f32_16x16x32_bf16(
              a[mt], b, (st == 0) ? Z : acc[mt][nt], 0, 0, 0);
      }
    }
  };

  // forward epilogue: a+=bias; z=softplus -> zbuf; s=sigmoid -> slab
  auto fwd_epi = [&](const float* biasp, u64* slab) {
    float bias[4];
#pragma unroll
    for (int nt = 0; nt < 4; ++nt) bias[nt] = biasp[(w * 4 + nt) * 16 + l15];
#pragma unroll
    for (int mt = 0; mt < 4; ++mt)
#pragma unroll
      for (int nt = 0; nt < 4; ++nt) {
        int n = (w * 4 + nt) * 16 + l15;
        f32x4 A = acc[mt][nt];
        u64 pack = 0;
#pragma unroll
        for (int r = 0; r < 4; ++r) {
          float a = A[r] + bias[nt];
          float t = __expf(-a);
          float u = 1.0f + t;
          float s = __builtin_amdgcn_rcpf(u);     // sigmoid(a)
          float z = a + __logf(u);                // softplus(a)
          pack |= (u64)f2b(s) << (16 * r);
          wrZ(mt * 16 + q * 4 + r, n, (u16)f2b(z));
        }
        slab[((blk * 8 + w) * 16 + mt * 4 + nt) * 64 + lane] = pack;
      }
  };
  auto d3_epi = [&](const float* biasp) {   // d3 = WzL * sigmoid(a3) -> zbuf
    float bias[4], wl[4];
#pragma unroll
    for (int nt = 0; nt < 4; ++nt) {
      bias[nt] = biasp[(w * 4 + nt) * 16 + l15];
      wl[nt] = WzL[(w * 4 + nt) * 16 + l15];
    }
#pragma unroll
    for (int mt = 0; mt < 4; ++mt)
#pragma unroll
      for (int nt = 0; nt < 4; ++nt) {
        int n = (w * 4 + nt) * 16 + l15;
        f32x4 A = acc[mt][nt];
#pragma unroll
        for (int r = 0; r < 4; ++r) {
          float a = A[r] + bias[nt];
          float t = __expf(-a);
          float s = __builtin_amdgcn_rcpf(1.0f + t);
          wrZ(mt * 16 + q * 4 + r, n, (u16)f2b(wl[nt] * s));
        }
      }
  };
  // d = g * s -> zbuf (slab read once; d never re-materialized to global)
  auto bwd_epi = [&](const u64* slab) {
    u64 v[4][4];
#pragma unroll
    for (int mt = 0; mt < 4; ++mt)
#pragma unroll
      for (int nt = 0; nt < 4; ++nt)
        v[mt][nt] = slab[((blk * 8 + w) * 16 + mt * 4 + nt) * 64 + lane];
#pragma unroll
    for (int mt = 0; mt < 4; ++mt)
#pragma unroll
      for (int nt = 0; nt < 4; ++nt) {
        int n = (w * 4 + nt) * 16 + l15;
        f32x4 A = acc[mt][nt];
#pragma unroll
        for (int r = 0; r < 4; ++r) {
          float s = b2f((u32)(v[mt][nt] >> (16 * r)) & 0xffffu);
          wrZ(mt * 16 + q * 4 + r, n, (u16)f2b(A[r] * s));
        }
      }
  };

  // grad mini-phase: park += zbuf(d) @ Wg (acc is DEAD here).
  // Wave w owns tiles t0=w, t1=w+8: mt = w&3, cols ct0=w>>2, ct1=ct0+2.
  auto minigrad = [&](const u16* Wg, bool init) {
    int mt = w & 3, c0 = w >> 2;
    bf16x8 g0[16], g1[16];
#pragma unroll
    for (int st = 0; st < 16; ++st)
      g0[st] = *(const bf16x8*)(Wg + (c0 * 16 + st) * 512 + lane * 8);
#pragma unroll
    for (int st = 0; st < 16; ++st)
      g1[st] = *(const bf16x8*)(Wg + ((c0 + 2) * 16 + st) * 512 + lane * 8);
    f32x4 t0 = Z, t1 = Z;
#pragma unroll
    for (int st = 0; st < 16; ++st) {
      bf16x8 a = ldA(mt, st);
      t0 = __builtin_amdgcn_mfma_f32_16x16x32_bf16(a, g0[st], t0, 0, 0, 0);
      t1 = __builtin_amdgcn_mfma_f32_16x16x32_bf16(a, g1[st], t1, 0, 0, 0);
    }
    if (init) {
      park[w * 64 + lane] = t0;
      park[(w + 8) * 64 + lane] = t1;
    } else {
      park[w * 64 + lane] += t0;
      park[(w + 8) * 64 + lane] += t1;
    }
  };

  // ---------------- forward ----------------
  __syncthreads();                          // xbuf ready
  fwdX(Wz0b, true);                         // a0 = x@Wz0^T
  stageW(Wz1b, 0, 0);                       // prestage; overlaps epilogue
  fwd_epi(bz0, slab0);
  __syncthreads();
  fwdH(Wz1b); fwdX(Wx0b, false);            // a1 = z0@Wz1^T + x@Wx0^T
  __syncthreads();
  stageW(Wz2b, 0, 0);
  fwd_epi(bx0, slab1);
  __syncthreads();
  fwdH(Wz2b); fwdX(Wx1b, false);
  __syncthreads();
  stageW(Wz3b, 0, 0);
  fwd_epi(bx1, slab2);
  __syncthreads();
  fwdH(Wz3b); fwdX(Wx2b, false);            // a3 (last use of xbuf)
  __syncthreads();
  stageW(Wz3t, 0, 0);                       // prestage bwd chain
  d3_epi(bx2);                              // d3 -> zbuf
  __syncthreads();
  // ---------------- backward ----------------
  minigrad(Wx2t, true);                     // park  = d3@Wx2t   (xbuf now dead)
  fwdH(Wz3t);                               // acc   = d3@Wz3
  __syncthreads();
  stageW(Wz2t, 0, 0);
  bwd_epi(slab2);                           // d2 -> zbuf
  __syncthreads();
  minigrad(Wx1t, false);                    // park += d2@Wx1t
  fwdH(Wz2t);                               // acc   = d2@Wz2
  __syncthreads();
  stageW(Wz1t, 0, 0);
  bwd_epi(slab1);                           // d1 -> zbuf
  __syncthreads();
  minigrad(Wx0t, false);                    // park += d1@Wx0t
  fwdH(Wz1t);                               // acc   = d1@Wz1
  __syncthreads();
  bwd_epi(slab0);                           // d0 -> zbuf
  __syncthreads();
  // ---- final: out = d0@Wz0t + park + WxL ----
  {
    int mt = w & 3, c0 = w >> 2;
    bf16x8 g0[16], g1[16];
#pragma unroll
    for (int st = 0; st < 16; ++st)
      g0[st] = *(const bf16x8*)(Wz0t + (c0 * 16 + st) * 512 + lane * 8);
#pragma unroll
    for (int st = 0; st < 16; ++st)
      g1[st] = *(const bf16x8*)(Wz0t + ((c0 + 2) * 16 + st) * 512 + lane * 8);
    f32x4 t0 = Z, t1 = Z;
#pragma unroll
    for (int st = 0; st < 16; ++st) {
      bf16x8 a = ldA(mt, st);
      t0 = __builtin_amdgcn_mfma_f32_16x16x32_bf16(a, g0[st], t0, 0, 0, 0);
      t1 = __builtin_amdgcn_mfma_f32_16x16x32_bf16(a, g1[st], t1, 0, 0, 0);
    }
    f32x4 p0 = park[w * 64 + lane];
    f32x4 p1 = park[(w + 8) * 64 + lane];
    float wx0 = WxL[c0 * 16 + l15];
    float wx1 = WxL[(c0 + 2) * 16 + l15];
#pragma unroll
    for (int r = 0; r < 4; ++r) {
      int row = blk * BM + mt * 16 + q * 4 + r;
      out[row * D + c0 * 16 + l15] = t0[r] + p0[r] + wx0;
      out[row * D + (c0 + 2) * 16 + l15] = t1[r] + p1[r] + wx1;
    }
  }
}

extern "C" void kernel_launch(void* const* d_in, const int* in_sizes, int n_in,
                              void* d_out, int out_size, void* d_ws, size_t ws_size,
                              hipStream_t stream) {
  const float* state = (const float*)d_in[0];
  const float* Wz0 = (const float*)d_in[1];
  const float* bz0 = (const float*)d_in[2];
  const float* Wz1 = (const float*)d_in[3];
  const float* Wz2 = (const float*)d_in[4];
  const float* Wz3 = (const float*)d_in[5];
  const float* WzL = (const float*)d_in[6];
  const float* Wx0 = (const float*)d_in[7];
  const float* bx0 = (const float*)d_in[8];
  const float* Wx1 = (const float*)d_in[9];
  const float* bx1 = (const float*)d_in[10];
  const float* Wx2 = (const float*)d_in[11];
  const float* bx2 = (const float*)d_in[12];
  const float* WxL = (const float*)d_in[13];

  if (ws_size < (size_t)WS_ELEMS * 2) {
    fill_sentinel<<<(out_size + 255) / 256, 256, 0, stream>>>((float*)d_out, out_size);
    return;
  }
  u16* wsw = (u16*)d_ws;
  prep_kernel<<<OFF_WEND / 256, 256, 0, stream>>>(Wz0, Wz1, Wz2, Wz3, Wx0, Wx1, Wx2, wsw);
  icnn_kernel<<<B_TOTAL / BM, 512, 0, stream>>>(state, bz0, bx0, bx1, bx2, WzL, WxL,
                                                wsw, (float*)d_out);
}